// Round 11
// baseline (28.012 us; speedup 1.0000x reference)
//
#include <hip/hip_runtime.h>
#include <math.h>

// Tropical (min-plus) matmul: out[b, j] = min_i (X[b, i] + W[j, i])
// X: [1024][512] fp32, W: [512][512] fp32, out: [1024][512] fp32.
//
// Round 11: geometry b16 x j128 (grid 64x4 = 256 = 1 block/CU), uniform-VMEM
// X delivery, W fully lane-resident, forced v_pk_add_f32.
//  - W per block: 128 j x 512 k = 256 KB (half of round 8) -> ~4.6K cyc VMEM.
//    Wave wid holds its whole 32-k chunk: w[8 grp][2 jq] = 16 float4 = 64 VGPR,
//    loaded ONCE (coalesced via WT4 pack), never reloaded.
//  - X: uniform-address global_load_dwordx4 (one 64B line broadcast to the
//    wave). Each X element is read exactly once per block (disjoint k-chunks).
//    NO Xs staging, NO staging barrier; vmcnt pipelining by the compiler.
//  - v_pk_add_f32 (inline asm; round 9's float2 '+' scalarized): per (4k, jq)
//    2 pk_add + 2 v_min3 = 4 VALU instr -> 1024 instr/wave = 8.2K cyc/SIMD.
//  - Partials: float2 (j, j+64) per lane -> 1 ds_write_b64/b; single barrier;
//    1024-thread combine, coalesced stores.
// LDS: part[16][16][64] float2 = 128 KB. VGPR ~112 (64 W + 32 acc + temps).

#define B_DIM   1024
#define IN_DIM  512
#define OUT_DIM 512

typedef float v2f __attribute__((ext_vector_type(2)));

__device__ __forceinline__ v2f mk2(float a, float b) { v2f r; r.x = a; r.y = b; return r; }

__device__ __forceinline__ v2f pk_add(v2f a, v2f b) {
    v2f d;
    asm("v_pk_add_f32 %0, %1, %2" : "=v"(d) : "v"(a), "v"(b));
    return d;
}

// ---------------- prepass: WT4[k4][j] = { W[j][4k4..4k4+3] } ----------------
__global__ __launch_bounds__(256)
void MinPlus_wt4_pack(const float* __restrict__ W, float4* __restrict__ WT4) {
    __shared__ float Ls[64][68];
    const int tid = threadIdx.x;
    const int j0 = blockIdx.x * 64;
    const int k0 = blockIdx.y * 64;

#pragma unroll
    for (int r = 0; r < 4; ++r) {
        const int jj = (tid >> 4) + r * 16;
        const int kq = tid & 15;
        const float4 v = *reinterpret_cast<const float4*>(&W[(j0 + jj) * IN_DIM + k0 + 4 * kq]);
        *reinterpret_cast<float4*>(&Ls[jj][4 * kq]) = v;
    }
    __syncthreads();

    const int jj  = tid & 63;
    const int k4b = tid >> 6;
#pragma unroll
    for (int r = 0; r < 4; ++r) {
        const int k4l = r * 4 + k4b;
        const float4 v = *reinterpret_cast<const float4*>(&Ls[jj][4 * k4l]);
        WT4[(size_t)(blockIdx.y * 16 + k4l) * OUT_DIM + j0 + jj] = v;
    }
}

// ---------------- main ----------------
__global__ __launch_bounds__(1024)
void MinPlus_70832600646269_kernel(const float* __restrict__ X,
                                   const float4* __restrict__ WT4,
                                   float* __restrict__ out)
{
    __shared__ float2 part[16][16][64];  // 128 KB: [k-chunk][b][lane] = (j, j+64)

    const int tid  = threadIdx.x;
    const int lane = tid & 63;
    const int wid  = tid >> 6;           // 0..15: k-chunk [32wid, 32wid+32)
    const int j0   = blockIdx.x * 128;
    const int b0   = blockIdx.y * 16;

    // ---- W resident: w[grp][jq], grp = k4-group in chunk, jq = j-half ----
    float4 w[8][2];
#pragma unroll
    for (int grp = 0; grp < 8; ++grp)
#pragma unroll
        for (int jq = 0; jq < 2; ++jq)
            w[grp][jq] = WT4[(size_t)(wid * 8 + grp) * OUT_DIM + j0 + jq * 64 + lane];

    float acc0[16], acc1[16];            // [b] for j-half 0 / 1 (static idx)
#pragma unroll
    for (int b = 0; b < 16; ++b) { acc0[b] = INFINITY; acc1[b] = INFINITY; }

    const float* __restrict__ xbase = X + (size_t)b0 * IN_DIM + wid * 32;

#pragma unroll
    for (int b = 0; b < 16; ++b) {
#pragma unroll
        for (int grp = 0; grp < 8; ++grp) {
            // uniform-address broadcast load: one 16B chunk of X row b0+b
            const float4 x = *reinterpret_cast<const float4*>(
                xbase + (size_t)b * IN_DIM + grp * 4);
            const v2f xlo = mk2(x.x, x.y);
            const v2f xhi = mk2(x.z, x.w);

            {
                const float4 u  = w[grp][0];
                const v2f   t0 = pk_add(mk2(u.x, u.y), xlo);
                const v2f   t1 = pk_add(mk2(u.z, u.w), xhi);
                acc0[b] = fminf(fminf(acc0[b], t0.x), t0.y);   // v_min3
                acc0[b] = fminf(fminf(acc0[b], t1.x), t1.y);   // v_min3
            }
            {
                const float4 u  = w[grp][1];
                const v2f   t0 = pk_add(mk2(u.x, u.y), xlo);
                const v2f   t1 = pk_add(mk2(u.z, u.w), xhi);
                acc1[b] = fminf(fminf(acc1[b], t0.x), t0.y);
                acc1[b] = fminf(fminf(acc1[b], t1.x), t1.y);
            }
        }
    }

    // ---- per-wave partials: one ds_write_b64 per b-row ----
#pragma unroll
    for (int b = 0; b < 16; ++b)
        part[wid][b][lane] = make_float2(acc0[b], acc1[b]);

    __syncthreads();

    // ---- combine 16 k-chunks: 1024 threads, one (b, lane) pair each ----
    {
        const int b = tid >> 6;          // 0..15
        const int l = tid & 63;
        float2 m = part[0][b][l];
#pragma unroll
        for (int p = 1; p < 16; ++p) {
            const float2 v = part[p][b][l];
            m.x = fminf(m.x, v.x);
            m.y = fminf(m.y, v.y);
        }
        float* orow = out + (size_t)(b0 + b) * OUT_DIM + j0;
        orow[l]      = m.x;
        orow[64 + l] = m.y;
    }
}

extern "C" void kernel_launch(void* const* d_in, const int* in_sizes, int n_in,
                              void* d_out, int out_size, void* d_ws, size_t ws_size,
                              hipStream_t stream) {
    const float* X = (const float*)d_in[0];
    const float* W = (const float*)d_in[1];
    float* out = (float*)d_out;
    float4* WT4 = (float4*)d_ws;   // 128 * 512 float4 = 1 MiB

    MinPlus_wt4_pack<<<dim3(OUT_DIM / 64, IN_DIM / 64), 256, 0, stream>>>(W, WT4);

    MinPlus_70832600646269_kernel<<<dim3(OUT_DIM / 128, B_DIM / 16), 1024, 0, stream>>>(X, WT4, out);
}

// Round 12
// 25.407 us; speedup vs baseline: 1.1025x; 1.1025x over previous
//
#include <hip/hip_runtime.h>
#include <math.h>

// Tropical (min-plus) matmul: out[b, j] = min_i (X[b, i] + W[j, i])
// X: [1024][512] fp32, W: [512][512] fp32, out: [1024][512] fp32.
//
// Round 12: k-on-lanes outer product. No LDS, no barriers, no broadcasts,
// no W-pack prepass — every broadcast-delivery scheme (r4 SMEM, r8 LDS,
// r10 hybrid, r11 uniform-VMEM) plateaued at ~20 us main.
//  - lane = (jp = lane>>5, kg = lane&31); lane covers k = s*128 + kg*4 .. +3
//    per slice s (4 slices = 512 k). All loads per-lane coalesced b128 from
//    the ORIGINAL X/W layouts.
//  - Wave owns 4 b x 8 j. acc[b][jt] = lane-partial min (jp halves give 2 j
//    per slot -> 16 slots = 32 outputs). Inner: 2 v_pk_add_f32 + 2 v_min3
//    per 4 triples = 1 VALU instr/triple -> 8.2K cyc/CU main floor.
//  - Epilogue: pack-merge butterfly over kg (shfl_xor d=16,8,4,2 + select,
//    then final xor1 self-min). Lane L ends holding merged value of slot
//    m = bitrev4((kg>>1)&15); store j = jb + (m&3)*2 + jp, b = bb + (m>>2).
//  - Block 512 thr = 8 waves = (2 jg x 4 bg) -> tile 16 b x 16 j.
//    Grid (512/16, 1024/16) = (32, 64) = 2048 blocks. ~60 VGPR, 0 LDS.

#define B_DIM   1024
#define IN_DIM  512
#define OUT_DIM 512

typedef float v2f __attribute__((ext_vector_type(2)));

__device__ __forceinline__ v2f mk2(float a, float b) { v2f r; r.x = a; r.y = b; return r; }

__device__ __forceinline__ v2f pk_add(v2f a, v2f b) {
    v2f d;
    asm("v_pk_add_f32 %0, %1, %2" : "=v"(d) : "v"(a), "v"(b));
    return d;
}

__global__ __launch_bounds__(512)
void MinPlus_70832600646269_kernel(const float* __restrict__ X,
                                   const float* __restrict__ W,
                                   float* __restrict__ out)
{
    const int tid  = threadIdx.x;
    const int lane = tid & 63;
    const int wid  = tid >> 6;        // 0..7
    const int jp   = lane >> 5;       // 0/1: j parity half
    const int kg   = lane & 31;       // k-group within slice

    const int jb = blockIdx.x * 16 + (wid >> 2) * 8;  // wave j-base (8 j: +jt*2+jp)
    const int bb = blockIdx.y * 16 + (wid & 3) * 4;   // wave b-base (4 b)

    float acc[4][4];                  // [b][jt], lane-partial mins
#pragma unroll
    for (int b = 0; b < 4; ++b)
#pragma unroll
        for (int jt = 0; jt < 4; ++jt) acc[b][jt] = INFINITY;

    const float* __restrict__ xp = X + (size_t)bb * IN_DIM + kg * 4;
    const float* __restrict__ wp = W + (size_t)(jb + jp) * IN_DIM + kg * 4;

#pragma unroll
    for (int s = 0; s < 4; ++s) {     // 4 k-slices of 128
        float4 x4[4], w4[4];
#pragma unroll
        for (int b = 0; b < 4; ++b)
            x4[b] = *reinterpret_cast<const float4*>(xp + (size_t)b * IN_DIM + s * 128);
#pragma unroll
        for (int jt = 0; jt < 4; ++jt)
            w4[jt] = *reinterpret_cast<const float4*>(wp + (size_t)(jt * 2) * IN_DIM + s * 128);

#pragma unroll
        for (int b = 0; b < 4; ++b) {
            const v2f xlo = mk2(x4[b].x, x4[b].y);
            const v2f xhi = mk2(x4[b].z, x4[b].w);
#pragma unroll
            for (int jt = 0; jt < 4; ++jt) {
                const v2f t0 = pk_add(mk2(w4[jt].x, w4[jt].y), xlo);
                const v2f t1 = pk_add(mk2(w4[jt].z, w4[jt].w), xhi);
                acc[b][jt] = fminf(fminf(acc[b][jt], t0.x), t0.y);   // v_min3
                acc[b][jt] = fminf(fminf(acc[b][jt], t1.x), t1.y);   // v_min3
            }
        }
    }

    // ---- pack-merge butterfly over kg: A[m] = acc[m>>2][m&3] ----
    float A[16];
#pragma unroll
    for (int m = 0; m < 16; ++m) A[m] = acc[m >> 2][m & 3];

    float B[8];
#pragma unroll
    for (int p = 0; p < 8; ++p) {     // d=16 -> slot bit0
        const float t = fminf(A[2 * p],     __shfl_xor(A[2 * p],     16));
        const float u = fminf(A[2 * p + 1], __shfl_xor(A[2 * p + 1], 16));
        B[p] = (lane & 16) ? u : t;
    }
    float C[4];
#pragma unroll
    for (int p = 0; p < 4; ++p) {     // d=8 -> slot bit1
        const float t = fminf(B[2 * p],     __shfl_xor(B[2 * p],     8));
        const float u = fminf(B[2 * p + 1], __shfl_xor(B[2 * p + 1], 8));
        C[p] = (lane & 8) ? u : t;
    }
    float D[2];
#pragma unroll
    for (int p = 0; p < 2; ++p) {     // d=4 -> slot bit2
        const float t = fminf(C[2 * p],     __shfl_xor(C[2 * p],     4));
        const float u = fminf(C[2 * p + 1], __shfl_xor(C[2 * p + 1], 4));
        D[p] = (lane & 4) ? u : t;
    }
    float E;
    {                                 // d=2 -> slot bit3
        const float t = fminf(D[0], __shfl_xor(D[0], 2));
        const float u = fminf(D[1], __shfl_xor(D[1], 2));
        E = (lane & 2) ? u : t;
    }
    E = fminf(E, __shfl_xor(E, 1));   // final: complete the kg-pair

    // lane holds slot m = bitrev4 of kg bits 4..1
    const int m = ((kg >> 4) & 1) | (((kg >> 3) & 1) << 1)
                | (((kg >> 2) & 1) << 2) | (((kg >> 1) & 1) << 3);
    if (!(lane & 1)) {
        const int b_loc = m >> 2;
        const int jt    = m & 3;
        out[(size_t)(bb + b_loc) * OUT_DIM + jb + jt * 2 + jp] = E;
    }
}

extern "C" void kernel_launch(void* const* d_in, const int* in_sizes, int n_in,
                              void* d_out, int out_size, void* d_ws, size_t ws_size,
                              hipStream_t stream) {
    const float* X = (const float*)d_in[0];
    const float* W = (const float*)d_in[1];
    float* out = (float*)d_out;

    dim3 grid(OUT_DIM / 16, B_DIM / 16);   // (32, 64) = 2048 blocks
    MinPlus_70832600646269_kernel<<<grid, 512, 0, stream>>>(X, W, out);
}

// Round 13
// 21.823 us; speedup vs baseline: 1.2836x; 1.1642x over previous
//
#include <hip/hip_runtime.h>
#include <math.h>

// Tropical (min-plus) matmul: out[b, j] = min_i (X[b, i] + W[j, i])
// X: [1024][512] fp32, W: [512][512] fp32, out: [1024][512] fp32.
//
// Round 13: fp16-packed arithmetic on the r8 broadcast skeleton.
// Rationale: every fp32 structure (r8 LDS-broadcast, r12 lane-resident) is
// operand-byte bound at >=12K cyc/CU. fp16 halves every pipe's byte count and
// v_pk_add_f16 + v_pk_min_f16 give 1 VALU instr/triple:
//   VALU 8.2K, X-LDS-reads 6.1K (512 b128 broadcasts/block, 8 k each),
//   W-VMEM 4.6K (256 KB/block), part/combine ~3K -> overlapped ~4-6 us main.
// Precision: |x|,|w| <= ~6; cvt + fp16 add error <= ~0.02 << 0.0906 threshold.
//  - Prepass (one kernel): Xh = fp16(X) elementwise; WT8[k8][j] = 8 k-halfs of
//    W row j (LDS-transpose tiles, coalesced both sides).
//  - Main: b8 x j256 tile, 16 waves, wave owns k-chunk 32 = 4 k8-quarters.
//    W ping-pong (4+4 uint4), X via uniform-address LDS broadcast b128.
//    acc packed (k-even/k-odd partial mins); epilogue mins the halves.
// LDS: Xs 8 KB + part 128 KB = 136 KB, 1 block/CU, grid (2 x 128) = 256.
// ws: WT8 512 KB @ 0, Xh 1 MB @ 512 KB -> 1.5 MB total.

#define B_DIM   1024
#define IN_DIM  512
#define OUT_DIM 512

typedef unsigned int uint;

__device__ __forceinline__ uint pk2(float a, float b) {
    unsigned short ua = __builtin_bit_cast(unsigned short, (_Float16)a);
    unsigned short ub = __builtin_bit_cast(unsigned short, (_Float16)b);
    return (uint)ua | ((uint)ub << 16);
}

__device__ __forceinline__ float h_lo(uint u) {
    return (float)__builtin_bit_cast(_Float16, (unsigned short)(u & 0xffff));
}
__device__ __forceinline__ float h_hi(uint u) {
    return (float)__builtin_bit_cast(_Float16, (unsigned short)(u >> 16));
}

__device__ __forceinline__ uint pk_add_h(uint a, uint b) {
    uint d;
    asm("v_pk_add_f16 %0, %1, %2" : "=v"(d) : "v"(a), "v"(b));
    return d;
}
__device__ __forceinline__ uint pk_min_h(uint a, uint b) {
    uint d;
    asm("v_pk_min_f16 %0, %1, %2" : "=v"(d) : "v"(a), "v"(b));
    return d;
}

// ---------------- prepass: pack X -> fp16, W -> WT8[k8][j] (transposed) ----
__global__ __launch_bounds__(256)
void MinPlus_pack_h(const float* __restrict__ X, const float* __restrict__ W,
                    uint* __restrict__ Xh, uint4* __restrict__ WT8) {
    const int tid = threadIdx.x;
    const int bid = blockIdx.x;

    if (bid < 64) {
        // ---- W tile (64 j x 64 k): load coalesced, transpose via LDS ----
        __shared__ float Ls[64][68];
        const int j0 = (bid & 7) * 64;
        const int k0 = (bid >> 3) * 64;
#pragma unroll
        for (int r = 0; r < 4; ++r) {
            const int jj = (tid >> 4) + r * 16;
            const int kq = tid & 15;
            const float4 v = *reinterpret_cast<const float4*>(&W[(j0 + jj) * IN_DIM + k0 + 4 * kq]);
            *reinterpret_cast<float4*>(&Ls[jj][4 * kq]) = v;
        }
        __syncthreads();
#pragma unroll
        for (int r = 0; r < 2; ++r) {
            const int idx = tid + r * 256;
            const int k8l = idx >> 6;       // 0..7
            const int jl  = idx & 63;
            const float4 a = *reinterpret_cast<const float4*>(&Ls[jl][8 * k8l]);
            const float4 b = *reinterpret_cast<const float4*>(&Ls[jl][8 * k8l + 4]);
            uint4 o;
            o.x = pk2(a.x, a.y); o.y = pk2(a.z, a.w);
            o.z = pk2(b.x, b.y); o.w = pk2(b.z, b.w);
            WT8[(size_t)(k0 / 8 + k8l) * OUT_DIM + j0 + jl] = o;
        }
    } else {
        // ---- X convert: blocks 64..319, 512 float4 each, fully coalesced ----
        const int cb = bid - 64;
        const float4* __restrict__ src = reinterpret_cast<const float4*>(X) + (size_t)cb * 512 + tid;
        uint2* __restrict__ dst = reinterpret_cast<uint2*>(Xh) + (size_t)cb * 512 + tid;
#pragma unroll
        for (int r = 0; r < 2; ++r) {
            const float4 v = src[r * 256];
            uint2 o;
            o.x = pk2(v.x, v.y);
            o.y = pk2(v.z, v.w);
            dst[r * 256] = o;
        }
    }
}

// ---------------- main ----------------
__global__ __launch_bounds__(1024)
void MinPlus_70832600646269_kernel(const uint* __restrict__ Xh,
                                   const uint4* __restrict__ WT8,
                                   float* __restrict__ out)
{
    __shared__ uint   Xs[8][256];        // 8 KB: rows b0..b0+7, 512 halfs each
    __shared__ float4 part[16][8][64];   // 128 KB: [k-chunk][b][lane]

    const int tid  = threadIdx.x;
    const int lane = tid & 63;
    const int wid  = tid >> 6;           // 0..15: k-chunk [32wid, 32wid+32)
    const int j0   = blockIdx.x * 256;
    const int b0   = blockIdx.y * 8;

    // ---- stage X tile: 8 KB = 512 uint4, threads 0..511, coalesced ----
    if (tid < 512)
        reinterpret_cast<uint4*>(&Xs[0][0])[tid] =
            reinterpret_cast<const uint4*>(Xh + (size_t)b0 * 256)[tid];

    uint acc2[8][4];                     // packed (k-even, k-odd) partial mins
#pragma unroll
    for (int b = 0; b < 8; ++b)
#pragma unroll
        for (int jq = 0; jq < 4; ++jq) acc2[b][jq] = 0x7C007C00u;  // +inf pair

    const uint4* __restrict__ wbase = WT8 + j0 + lane;
    const int g0 = wid * 4;              // first k8-group of this wave's chunk

    uint4 wA[4], wB[4];
#pragma unroll
    for (int jq = 0; jq < 4; ++jq)
        wA[jq] = wbase[(size_t)g0 * OUT_DIM + jq * 64];

    __syncthreads();                     // Xs ready

#define COMPUTE(WBUF, QT)                                                       \
    {                                                                           \
        _Pragma("unroll")                                                       \
        for (int b = 0; b < 8; ++b) {                                           \
            const uint4 x = *reinterpret_cast<const uint4*>(                    \
                &Xs[b][wid * 16 + (QT) * 4]);                                   \
            _Pragma("unroll")                                                   \
            for (int jq = 0; jq < 4; ++jq) {                                    \
                acc2[b][jq] = pk_min_h(acc2[b][jq], pk_add_h(WBUF[jq].x, x.x)); \
                acc2[b][jq] = pk_min_h(acc2[b][jq], pk_add_h(WBUF[jq].y, x.y)); \
                acc2[b][jq] = pk_min_h(acc2[b][jq], pk_add_h(WBUF[jq].z, x.z)); \
                acc2[b][jq] = pk_min_h(acc2[b][jq], pk_add_h(WBUF[jq].w, x.w)); \
            }                                                                   \
        }                                                                       \
    }

    // ---- 4 k8-quarters, ping-pong W prefetch (static buffers) ----
#pragma unroll
    for (int qt = 0; qt < 4; qt += 2) {
#pragma unroll
        for (int jq = 0; jq < 4; ++jq)
            wB[jq] = wbase[(size_t)(g0 + qt + 1) * OUT_DIM + jq * 64];

        COMPUTE(wA, qt)

        if (qt < 2) {
#pragma unroll
            for (int jq = 0; jq < 4; ++jq)
                wA[jq] = wbase[(size_t)(g0 + qt + 2) * OUT_DIM + jq * 64];
        }

        COMPUTE(wB, qt + 1)
    }
#undef COMPUTE

    // ---- epilogue: min packed halves -> f32, one ds_write_b128 per b ----
#pragma unroll
    for (int b = 0; b < 8; ++b) {
        float4 o;
        o.x = fminf(h_lo(acc2[b][0]), h_hi(acc2[b][0]));
        o.y = fminf(h_lo(acc2[b][1]), h_hi(acc2[b][1]));
        o.z = fminf(h_lo(acc2[b][2]), h_hi(acc2[b][2]));
        o.w = fminf(h_lo(acc2[b][3]), h_hi(acc2[b][3]));
        part[wid][b][lane] = o;
    }

    __syncthreads();

    // ---- combine 16 k-chunks: threads 0..511, b128 reads, coalesced stores ----
    if (tid < 512) {
        const int b = tid >> 6;
        const int l = tid & 63;
        float4 m = part[0][b][l];
#pragma unroll
        for (int p = 1; p < 16; ++p) {
            const float4 v = part[p][b][l];
            m.x = fminf(m.x, v.x);
            m.y = fminf(m.y, v.y);
            m.z = fminf(m.z, v.z);
            m.w = fminf(m.w, v.w);
        }
        float* orow = out + (size_t)(b0 + b) * OUT_DIM + j0;
        orow[l]       = m.x;
        orow[64 + l]  = m.y;
        orow[128 + l] = m.z;
        orow[192 + l] = m.w;
    }
}

extern "C" void kernel_launch(void* const* d_in, const int* in_sizes, int n_in,
                              void* d_out, int out_size, void* d_ws, size_t ws_size,
                              hipStream_t stream) {
    const float* X = (const float*)d_in[0];
    const float* W = (const float*)d_in[1];
    float* out = (float*)d_out;

    uint4* WT8 = (uint4*)d_ws;                              // 512 KB
    uint*  Xh  = (uint*)((char*)d_ws + (512 << 10));        // 1 MB

    MinPlus_pack_h<<<dim3(64 + 256), 256, 0, stream>>>(X, W, Xh, WT8);

    MinPlus_70832600646269_kernel<<<dim3(OUT_DIM / 256, B_DIM / 8), 1024, 0, stream>>>(Xh, WT8, out);
}